// Round 4
// baseline (160.716 us; speedup 1.0000x reference)
//
#include <hip/hip_runtime.h>
#include <hip/hip_bf16.h>
#include <math.h>

#define NPTS 32768
#define C 64
#define K 16
#define NB2 512           // sred partial blocks
#define NB2R 64           // after sred2 hierarchical reduce
#define NTAB 512          // table cells for the per-k PWL function F_kc(t)
#define BN_INV 0.99999500003749968f   // 1/sqrt(1+1e-5)

__device__ __forceinline__ float safediv_n2n(float a, float b) {
    float q = a / b;
    if (isnan(q)) return 0.0f;
    if (isinf(q)) return copysignf(3.402823466e38f, q);
    return q;
}

// ---------------------------------------------------------------------------
// K1: projections, thread = point. acc[64] in VGPRs; W rows are wave-uniform
// -> scalar cache (s_load); activation reads fully coalesced (256B/instr).
// grid (128, 3), block 256.
// ---------------------------------------------------------------------------
__global__ __launch_bounds__(256) void proj2_kernel(
    const float* __restrict__ x, const float* __restrict__ y,
    const float* __restrict__ Wq, const float* __restrict__ bq,
    const float* __restrict__ Wk, const float* __restrict__ bk,
    const float* __restrict__ Wv, const float* __restrict__ bv,
    float* __restrict__ xq, float* __restrict__ yk,
    __hip_bfloat16* __restrict__ yvb)
{
    const int dir = blockIdx.y;
    const float* __restrict__ in   = (dir == 0) ? x  : y;
    const float* __restrict__ W    = (dir == 0) ? Wq : (dir == 1) ? Wk : Wv;
    const float* __restrict__ bias = (dir == 0) ? bq : (dir == 1) ? bk : bv;

    const int n = blockIdx.x * 256 + threadIdx.x;

    float acc[C];
    #pragma unroll
    for (int j = 0; j < C; ++j) acc[j] = bias[j];

    float xv = in[n];                       // c = 0
    #pragma unroll 2
    for (int c = 0; c < C; ++c) {
        const float xn = (c < C - 1) ? in[(c + 1) * NPTS + n] : 0.0f;  // prefetch
        const float* wr = W + c * C;        // wave-uniform -> s_load
        #pragma unroll
        for (int j = 0; j < C; ++j) acc[j] = fmaf(xv, wr[j], acc[j]);
        xv = xn;
    }

    if (dir == 2) {
        unsigned pk2[C / 2];
        #pragma unroll
        for (int j = 0; j < C; j += 2) {
            __hip_bfloat16 h0 = __float2bfloat16(acc[j]);
            __hip_bfloat16 h1 = __float2bfloat16(acc[j + 1]);
            pk2[j / 2] = (unsigned)*(unsigned short*)&h0 |
                         ((unsigned)*(unsigned short*)&h1 << 16);
        }
        uint4* dst = (uint4*)((unsigned short*)yvb + (size_t)n * C);
        #pragma unroll
        for (int q = 0; q < C / 8; ++q)
            dst[q] = make_uint4(pk2[q * 4], pk2[q * 4 + 1], pk2[q * 4 + 2], pk2[q * 4 + 3]);
    } else {
        float* __restrict__ out = (dir == 0) ? xq : yk;
        float4* dst = (float4*)(out + (size_t)n * C);
        #pragma unroll
        for (int q = 0; q < C / 4; ++q)
            dst[q] = make_float4(acc[q * 4], acc[q * 4 + 1], acc[q * 4 + 2], acc[q * 4 + 3]);
    }
}

// ---------------------------------------------------------------------------
// K1b: xuni (flat-reshape matvec + bn + relu) and xyz packing.
// grid 512, block 256.
// ---------------------------------------------------------------------------
__global__ __launch_bounds__(256) void aux_kernel(
    const float* __restrict__ x, const float* __restrict__ y_xyz,
    const float* __restrict__ Wu, const float* __restrict__ bu,
    const float* __restrict__ gu, const float* __restrict__ bnu,
    float* __restrict__ xu, float4* __restrict__ pk)
{
    const int lane = threadIdx.x & 63;
    const int wave = threadIdx.x >> 6;

    const float wul = Wu[lane];
    const float bnscale = gu[0] * BN_INV;
    const float bu0 = bu[0], bnu0 = bnu[0];
    #pragma unroll 4
    for (int i = 0; i < 16; ++i) {
        const int m = blockIdx.x * 64 + wave * 16 + i;
        float v = x[m * 64 + lane] * wul;
        #pragma unroll
        for (int off = 32; off > 0; off >>= 1) v += __shfl_xor(v, off, 64);
        if (lane == 0) {
            float u = (v + bu0) * bnscale + bnu0;
            xu[m] = fmaxf(u, 0.0f);
        }
    }
    if (wave == 0) {
        const int p = blockIdx.x * 64 + lane;
        pk[p] = make_float4(y_xyz[p], y_xyz[NPTS + p], y_xyz[2 * NPTS + p], 0.0f);
    }
}

// ---------------------------------------------------------------------------
// K2: partial S[c][k] = sum_n (y_k[idx[n,k]][c] - x_q[n][c]) * xu[n]
// ---------------------------------------------------------------------------
__global__ __launch_bounds__(256) void sred_kernel(
    const float* __restrict__ xq, const float* __restrict__ yk,
    const float* __restrict__ xu, const int* __restrict__ idx,
    float* __restrict__ partG)
{
    const int lane = threadIdx.x & 63;
    const int wave = threadIdx.x >> 6;
    const int gw = blockIdx.x * 4 + wave;
    const int nwv = NB2 * 4;
    float g[K];
    #pragma unroll
    for (int k = 0; k < K; ++k) g[k] = 0.0f;
    for (int n = gw; n < NPTS; n += nwv) {
        const float xuv = xu[n];
        if (xuv != 0.0f) {
            const float xqv = xq[n * C + lane];
            #pragma unroll
            for (int k = 0; k < K; ++k) {
                const int id = idx[n * K + k];
                g[k] = fmaf(yk[id * C + lane] - xqv, xuv, g[k]);
            }
        }
    }
    __shared__ float red[4][K][C];
    #pragma unroll
    for (int k = 0; k < K; ++k) red[wave][k][lane] = g[k];
    __syncthreads();
    if (wave == 0) {
        #pragma unroll
        for (int k = 0; k < K; ++k) {
            float s = red[0][k][lane] + red[1][k][lane] + red[2][k][lane] + red[3][k][lane];
            partG[blockIdx.x * (K * C) + k * C + lane] = s;
        }
    }
}

// ---------------------------------------------------------------------------
// K2a: hierarchical reduce 512 -> 64 partials (deterministic, no atomics)
// ---------------------------------------------------------------------------
__global__ __launch_bounds__(1024) void sred2_kernel(
    const float* __restrict__ partG, float* __restrict__ part2)
{
    const int j = blockIdx.x;       // 0..63
    const int t = threadIdx.x;      // 0..1023
    float s = 0.0f;
    #pragma unroll
    for (int i = 0; i < NB2 / NB2R; ++i)
        s += partG[(size_t)(j + NB2R * i) * (K * C) + t];
    part2[(size_t)j * (K * C) + t] = s;
}

// ---------------------------------------------------------------------------
// K2b: reduce 64 partials, softmax over k -> wd[c][k], awdT[k][c]=a_p[k]*wd
// ---------------------------------------------------------------------------
__global__ __launch_bounds__(1024) void wd_kernel(
    const float* __restrict__ part2, const float* __restrict__ a_p,
    float* __restrict__ wd, float* __restrict__ awdT)
{
    __shared__ float S[K][C];
    const int t = threadIdx.x;          // t = k*64 + c
    {
        float s = 0.0f;
        #pragma unroll 8
        for (int b = 0; b < NB2R; ++b) s += part2[b * (K * C) + t];
        S[0][t] = s;
    }
    __syncthreads();
    if (t < C) {
        const int c = t;
        float v[K];
        float m = -3.402823466e38f;
        #pragma unroll
        for (int k = 0; k < K; ++k) { v[k] = S[k][c]; m = fmaxf(m, v[k]); }
        float sum = 0.0f;
        #pragma unroll
        for (int k = 0; k < K; ++k) { v[k] = expf(v[k] - m); sum += v[k]; }
        const float r = 1.0f / sum;
        #pragma unroll
        for (int k = 0; k < K; ++k) {
            const float wv = v[k] * r;
            wd[c * K + k] = wv;
            awdT[k * C + c] = a_p[k] * wv;
        }
    }
}

// ---------------------------------------------------------------------------
// K3: w_e[n][k] = softmax_k( sum_c y[c][n] * wd[c][k] )
// ---------------------------------------------------------------------------
__global__ __launch_bounds__(256) void we_kernel(
    const float* __restrict__ y, const float* __restrict__ wd,
    float* __restrict__ we)
{
    __shared__ float wds[C][K];
    const int lane = threadIdx.x & 63;
    const int wave = threadIdx.x >> 6;
    for (int i = threadIdx.x; i < C * K; i += 256) wds[0][i] = wd[i];
    __syncthreads();

    const int n = (blockIdx.x * 4 + wave) * 64 + lane;
    float L[K];
    #pragma unroll
    for (int k = 0; k < K; ++k) L[k] = 0.0f;
    for (int c = 0; c < C; ++c) {
        const float yv = y[c * NPTS + n];
        float wa[K];
        ((float4*)wa)[0] = ((const float4*)&wds[c][0])[0];
        ((float4*)wa)[1] = ((const float4*)&wds[c][0])[1];
        ((float4*)wa)[2] = ((const float4*)&wds[c][0])[2];
        ((float4*)wa)[3] = ((const float4*)&wds[c][0])[3];
        #pragma unroll
        for (int k = 0; k < K; ++k) L[k] = fmaf(yv, wa[k], L[k]);
    }
    float m = L[0];
    #pragma unroll
    for (int k = 1; k < K; ++k) m = fmaxf(m, L[k]);
    float sum = 0.0f;
    #pragma unroll
    for (int k = 0; k < K; ++k) { L[k] = expf(L[k] - m); sum += L[k]; }
    const float r = 1.0f / sum;
    float* dst = we + (size_t)n * K;
    ((float4*)dst)[0] = make_float4(L[0]*r, L[1]*r, L[2]*r, L[3]*r);
    ((float4*)dst)[1] = make_float4(L[4]*r, L[5]*r, L[6]*r, L[7]*r);
    ((float4*)dst)[2] = make_float4(L[8]*r, L[9]*r, L[10]*r, L[11]*r);
    ((float4*)dst)[3] = make_float4(L[12]*r, L[13]*r, L[14]*r, L[15]*r);
}

// ---------------------------------------------------------------------------
// K3b: tabulate F_kc(t) (2-layer PWL map of scalar t) at t=i/NTAB, i=0..NTAB
// ---------------------------------------------------------------------------
__global__ __launch_bounds__(64) void tab_kernel(
    const float* __restrict__ awdT, const float* __restrict__ b_p,
    const float* __restrict__ Ww1, const float* __restrict__ bw1,
    const float* __restrict__ Ww2, const float* __restrict__ bw2,
    const float* __restrict__ gw1, const float* __restrict__ bw1b,
    const float* __restrict__ gw2, const float* __restrict__ bw2b,
    float* __restrict__ tab)
{
    const int lane = threadIdx.x;
    const int k  = blockIdx.y;
    const int i0 = blockIdx.x * 16;

    const float aw = awdT[k * C + lane];
    const float bp = b_p[k * C + lane];
    const float gs1 = gw1[lane] * BN_INV, bb1 = bw1b[lane], bw1c = bw1[lane];
    const float gs2 = gw2[lane] * BN_INV, bb2 = bw2b[lane], bw2c = bw2[lane];

    float w1c[C], w2c[C];
    #pragma unroll
    for (int c = 0; c < C; ++c) { w1c[c] = Ww1[c * C + lane]; w2c[c] = Ww2[c * C + lane]; }

    __shared__ float hs[16][C];

    #pragma unroll
    for (int r = 0; r < 16; ++r) {
        const float t = (float)(i0 + r) * (1.0f / NTAB);
        const float wv = fmaf(bp, t, aw);
        hs[r][lane] = fmaxf(fmaf(wv, gs1, bb1), 0.0f);
    }
    __syncthreads();

    float o[16];
    #pragma unroll
    for (int r = 0; r < 16; ++r) o[r] = bw1c;
    #pragma unroll
    for (int c4 = 0; c4 < 16; ++c4) {
        #pragma unroll
        for (int r = 0; r < 16; ++r) {
            const float4 hv = *(const float4*)&hs[r][c4 * 4];
            o[r] = fmaf(hv.x, w1c[c4 * 4 + 0], o[r]);
            o[r] = fmaf(hv.y, w1c[c4 * 4 + 1], o[r]);
            o[r] = fmaf(hv.z, w1c[c4 * 4 + 2], o[r]);
            o[r] = fmaf(hv.w, w1c[c4 * 4 + 3], o[r]);
        }
    }
    __syncthreads();
    #pragma unroll
    for (int r = 0; r < 16; ++r)
        hs[r][lane] = fmaxf(fmaf(o[r], gs2, bb2), 0.0f);
    __syncthreads();
    #pragma unroll
    for (int r = 0; r < 16; ++r) o[r] = bw2c;
    #pragma unroll
    for (int c4 = 0; c4 < 16; ++c4) {
        #pragma unroll
        for (int r = 0; r < 16; ++r) {
            const float4 hv = *(const float4*)&hs[r][c4 * 4];
            o[r] = fmaf(hv.x, w2c[c4 * 4 + 0], o[r]);
            o[r] = fmaf(hv.y, w2c[c4 * 4 + 1], o[r]);
            o[r] = fmaf(hv.z, w2c[c4 * 4 + 2], o[r]);
            o[r] = fmaf(hv.w, w2c[c4 * 4 + 3], o[r]);
        }
    }
    #pragma unroll
    for (int r = 0; r < 16; ++r) {
        const int i = i0 + r;
        if (i <= NTAB) tab[(k * (NTAB + 1) + i) * C + lane] = o[r];
    }
}

// ---------------------------------------------------------------------------
// K4 (hot): per point n (one wave, lane = channel c). Software-pipelined.
// ---------------------------------------------------------------------------
__global__ __launch_bounds__(256) void main3_kernel(
    const int* __restrict__ idx, const float4* __restrict__ pk,
    const __hip_bfloat16* __restrict__ yvb, const float* __restrict__ we,
    const float* __restrict__ tab, const float* __restrict__ d_p,
    const float* __restrict__ Wa1, const float* __restrict__ ba1,
    const float* __restrict__ ga, const float* __restrict__ bna,
    const float* __restrict__ Wa2, const float* __restrict__ ba2,
    const float* __restrict__ Wp1, const float* __restrict__ bp1,
    const float* __restrict__ gp, const float* __restrict__ bnp,
    const float* __restrict__ Wp2, const float* __restrict__ bp2,
    float* __restrict__ out)
{
    const int lane = threadIdx.x & 63;
    const int wave = threadIdx.x >> 6;

    __shared__ float geo[4][K][8];    // [1..3] af-features, [4..6] pr-features
    __shared__ float prm[36];

    if (threadIdx.x < 36) {
        const int t = threadIdx.x;
        float v;
        if (t < 9)       v = Wa1[t];
        else if (t < 12) v = ba1[t - 9];
        else if (t < 21) v = Wp1[t - 12];
        else if (t < 24) v = bp1[t - 21];
        else if (t < 27) v = ga[t - 24];
        else if (t < 30) v = bna[t - 27];
        else if (t < 33) v = gp[t - 30];
        else             v = bnp[t - 33];
        prm[t] = v;
    }
    __syncthreads();

    const float ba2c = ba2[lane], bp2c = bp2[lane];
    float wa2c[3], wp2c[3];
    #pragma unroll
    for (int d = 0; d < 3; ++d) { wa2c[d] = Wa2[d * C + lane]; wp2c[d] = Wp2[d * C + lane]; }
    float dpk[K];
    #pragma unroll
    for (int k = 0; k < K; ++k) dpk[k] = d_p[k * C + lane];

    const int gw = blockIdx.x * 4 + wave;
    const int nwv = gridDim.x * 4;
    const ushort* __restrict__ yvu_base = (const ushort*)yvb;

    // ---- prologue prefetch ----
    int n = gw;
    int idv = idx[n * K + (lane & 15)];
    float4 self = pk[n];
    float4 wev0 = ((const float4*)(we + (size_t)n * K))[0];
    float4 wev1 = ((const float4*)(we + (size_t)n * K))[1];
    float4 wev2 = ((const float4*)(we + (size_t)n * K))[2];
    float4 wev3 = ((const float4*)(we + (size_t)n * K))[3];

    while (n < NPTS) {
        const int n_next = n + nwv;

        // ---- dependent gathers for current point (issued first) ----
        const float4 nb = pk[idv];
        ushort yvu[K];
        #pragma unroll
        for (int k = 0; k < K; ++k) {
            const int idk = __shfl(idv, k, 64);
            yvu[k] = yvu_base[(size_t)idk * C + lane];
        }

        // ---- table loads (depend only on prefetched we) ----
        float wearr[K];
        ((float4*)wearr)[0] = wev0;
        ((float4*)wearr)[1] = wev1;
        ((float4*)wearr)[2] = wev2;
        ((float4*)wearr)[3] = wev3;
        float tv0[K], tv1[K], fr[K];
        #pragma unroll
        for (int k = 0; k < K; ++k) {
            const float u = wearr[k] * (float)NTAB;
            int ic = (int)u;
            ic = (ic < 0) ? 0 : (ic > NTAB - 1 ? NTAB - 1 : ic);
            fr[k] = u - (float)ic;
            const float* tp = tab + ((size_t)(k * (NTAB + 1) + ic) << 6) + lane;
            tv0[k] = tp[0];
            tv1[k] = tp[C];
        }

        // ---- prefetch next point's independent loads ----
        int idv_n = 0;
        float4 self_n = make_float4(0.f, 0.f, 0.f, 0.f);
        float4 wen0 = self_n, wen1 = self_n, wen2 = self_n, wen3 = self_n;
        if (n_next < NPTS) {
            idv_n  = idx[n_next * K + (lane & 15)];
            self_n = pk[n_next];
            wen0 = ((const float4*)(we + (size_t)n_next * K))[0];
            wen1 = ((const float4*)(we + (size_t)n_next * K))[1];
            wen2 = ((const float4*)(we + (size_t)n_next * K))[2];
            wen3 = ((const float4*)(we + (size_t)n_next * K))[3];
        }

        // ---- geometry (all lanes compute for k = lane&15; lanes<16 write) ----
        {
            const float px = nb.x - self.x;
            const float py = nb.y - self.y;
            const float pz = nb.z - self.z;
            const float ed  = sqrtf(px * px + py * py + pz * pz);
            const float exy = sqrtf(px * px + py * py);
            const float cose = safediv_n2n(exy, ed);
            const float cosa = safediv_n2n(py, exy);
            float gv[6];
            #pragma unroll
            for (int d = 0; d < 3; ++d) {
                const float a = ed * prm[d] + cosa * prm[3 + d] + cose * prm[6 + d] + prm[9 + d];
                gv[d] = fmaxf(a * (prm[24 + d] * BN_INV) + prm[27 + d], 0.0f);
                const float p = px * prm[12 + d] + py * prm[15 + d] + pz * prm[18 + d] + prm[21 + d];
                gv[3 + d] = fmaxf(p * (prm[30 + d] * BN_INV) + prm[33 + d], 0.0f);
            }
            if (lane < K) {
                float* g = &geo[wave][lane][0];
                g[1] = gv[0]; g[2] = gv[1]; g[3] = gv[2];
                g[4] = gv[3]; g[5] = gv[4]; g[6] = gv[5];
            }
        }

        // ---- w2 lerp + softmax over k ----
        float w2[K];
        #pragma unroll
        for (int k = 0; k < K; ++k) w2[k] = fmaf(fr[k], tv1[k] - tv0[k], tv0[k]);
        float m = w2[0];
        #pragma unroll
        for (int k = 1; k < K; ++k) m = fmaxf(m, w2[k]);
        float sum = 0.0f;
        #pragma unroll
        for (int k = 0; k < K; ++k) { w2[k] = __expf(w2[k] - m); sum += w2[k]; }
        const float r = 1.0f / sum;

        // ---- epilogue ----
        float acc = 0.0f;
        #pragma unroll
        for (int k = 0; k < K; ++k) {
            const float4 g0 = *(const float4*)&geo[wave][k][0];
            const float4 g1 = *(const float4*)&geo[wave][k][4];
            const float afc = fmaf(g0.y, wa2c[0], fmaf(g0.z, wa2c[1], fmaf(g0.w, wa2c[2], ba2c)));
            float prc = fmaf(g1.x, wp2c[0], fmaf(g1.y, wp2c[1], fmaf(g1.z, wp2c[2], bp2c)));
            prc = fmaf(dpk[k], afc, prc);
            const float yvf = __uint_as_float((unsigned)yvu[k] << 16);
            acc = fmaf(yvf + prc, w2[k] * r, acc);
        }
        out[(size_t)n * C + lane] = acc;

        // ---- rotate pipeline ----
        n = n_next;
        idv = idv_n;
        self = self_n;
        wev0 = wen0; wev1 = wen1; wev2 = wen2; wev3 = wen3;
    }
}

// ---------------------------------------------------------------------------
extern "C" void kernel_launch(void* const* d_in, const int* in_sizes, int n_in,
                              void* d_out, int out_size, void* d_ws, size_t ws_size,
                              hipStream_t stream)
{
    (void)in_sizes; (void)n_in; (void)out_size; (void)ws_size;
    const float* x     = (const float*)d_in[0];
    const float* y     = (const float*)d_in[1];
    const float* y_xyz = (const float*)d_in[2];
    const int*   idx   = (const int*)d_in[3];
    const float* Wq = (const float*)d_in[4];  const float* bq = (const float*)d_in[5];
    const float* Wk = (const float*)d_in[6];  const float* bk = (const float*)d_in[7];
    const float* Wv = (const float*)d_in[8];  const float* bv = (const float*)d_in[9];
    const float* Wu = (const float*)d_in[10]; const float* bu = (const float*)d_in[11];
    const float* gu = (const float*)d_in[12]; const float* bnu = (const float*)d_in[13];
    const float* Wp1 = (const float*)d_in[14]; const float* bp1 = (const float*)d_in[15];
    const float* gp  = (const float*)d_in[16]; const float* bnp = (const float*)d_in[17];
    const float* Wp2 = (const float*)d_in[18]; const float* bp2 = (const float*)d_in[19];
    const float* Wa1 = (const float*)d_in[20]; const float* ba1 = (const float*)d_in[21];
    const float* ga  = (const float*)d_in[22]; const float* bna = (const float*)d_in[23];
    const float* Wa2 = (const float*)d_in[24]; const float* ba2 = (const float*)d_in[25];
    const float* gw1 = (const float*)d_in[26]; const float* bw1b = (const float*)d_in[27];
    const float* Ww1 = (const float*)d_in[28]; const float* bw1 = (const float*)d_in[29];
    const float* gw2 = (const float*)d_in[30]; const float* bw2b = (const float*)d_in[31];
    const float* Ww2 = (const float*)d_in[32]; const float* bw2 = (const float*)d_in[33];
    const float* a_p = (const float*)d_in[34];
    const float* b_p = (const float*)d_in[35];
    const float* d_p = (const float*)d_in[36];
    float* out = (float*)d_out;

    float* ws = (float*)d_ws;
    // layout (floats): xq 2M | yk 2M | yv(bf16) 1M | pk 128K(f4) | xu 32K |
    //                  partG 512K | part2 64K | wd 1K | awdT 1K
    float* xq    = ws;                            // dead after sred
    float* we    = ws;                            // aliases xq (written later)
    float* yk    = ws + 2097152;                  // dead after sred
    float* tab   = ws + 2097152;                  // aliases yk (written later)
    __hip_bfloat16* yvb = (__hip_bfloat16*)(ws + 2 * 2097152);
    float4* pk   = (float4*)(ws + 2 * 2097152 + 1048576);
    float* xu    = ws + 2 * 2097152 + 1048576 + 131072;
    float* partG = xu + NPTS;                     // 512*1024
    float* part2 = partG + NB2 * K * C;           // 64*1024
    float* wd    = part2 + NB2R * K * C;          // 1024
    float* awdT  = wd + C * K;                    // 1024

    proj2_kernel<<<dim3(NPTS / 256, 3), 256, 0, stream>>>(
        x, y, Wq, bq, Wk, bk, Wv, bv, xq, yk, yvb);
    aux_kernel<<<NPTS / 64, 256, 0, stream>>>(x, y_xyz, Wu, bu, gu, bnu, xu, pk);
    sred_kernel<<<NB2, 256, 0, stream>>>(xq, yk, xu, idx, partG);
    sred2_kernel<<<NB2R, 1024, 0, stream>>>(partG, part2);
    wd_kernel<<<1, 1024, 0, stream>>>(part2, a_p, wd, awdT);
    we_kernel<<<NPTS / 256, 256, 0, stream>>>(y, wd, we);
    tab_kernel<<<dim3(33, 16), 64, 0, stream>>>(awdT, b_p, Ww1, bw1, Ww2, bw2,
                                                gw1, bw1b, gw2, bw2b, tab);
    main3_kernel<<<2048, 256, 0, stream>>>(idx, pk, yvb, we, tab, d_p,
        Wa1, ba1, ga, bna, Wa2, ba2, Wp1, bp1, gp, bnp, Wp2, bp2, out);
}

// Round 5
// 130.615 us; speedup vs baseline: 1.2305x; 1.2305x over previous
//
#include <hip/hip_runtime.h>
#include <hip/hip_bf16.h>
#include <math.h>

#define NPTS 32768
#define C 64
#define K 16
#define NB2 512           // sred partial blocks
#define NB2R 64           // after sred2 hierarchical reduce
#define NTAB 512          // table cells for the per-k PWL function F_kc(t)
#define BN_INV 0.99999500003749968f   // 1/sqrt(1+1e-5)

__device__ __forceinline__ float safediv_n2n(float a, float b) {
    float q = a / b;
    if (isnan(q)) return 0.0f;
    if (isinf(q)) return copysignf(3.402823466e38f, q);
    return q;
}

// ---------------------------------------------------------------------------
// K1: projections. grid (NPTS/64, 3), block 256 (4 waves).
// Stage 64x64 activation tile in LDS via coalesced loads; each wave computes
// 16 points, lane = output col j; activations read as uniform ds_read_b128
// broadcasts (conflict-free). acc[16] per lane stays in VGPRs.
// ---------------------------------------------------------------------------
__global__ __launch_bounds__(256) void proj3_kernel(
    const float* __restrict__ x, const float* __restrict__ y,
    const float* __restrict__ Wq, const float* __restrict__ bq,
    const float* __restrict__ Wk, const float* __restrict__ bk,
    const float* __restrict__ Wv, const float* __restrict__ bv,
    float* __restrict__ xq, float* __restrict__ yk,
    __hip_bfloat16* __restrict__ yvb)
{
    const int dir = blockIdx.y;
    const float* __restrict__ in   = (dir == 0) ? x  : y;
    const float* __restrict__ W    = (dir == 0) ? Wq : (dir == 1) ? Wk : Wv;
    const float* __restrict__ bias = (dir == 0) ? bq : (dir == 1) ? bk : bv;

    const int lane = threadIdx.x & 63;
    const int wave = threadIdx.x >> 6;
    const int n0 = blockIdx.x * 64;

    __shared__ float hs[C][C];          // [c][n_local], 16 KB

    // ---- stage activation tile (coalesced 256B per wave-instr) ----
    #pragma unroll
    for (int i = 0; i < 16; ++i) {
        const int c = i * 4 + wave;
        hs[c][lane] = in[(size_t)c * NPTS + n0 + lane];
    }
    __syncthreads();

    // ---- compute: wave handles points p0..p0+15, lane = out col ----
    const int p0 = wave * 16;
    float acc[16];
    const float b = bias[lane];
    #pragma unroll
    for (int i = 0; i < 16; ++i) acc[i] = b;

    #pragma unroll
    for (int c = 0; c < C; ++c) {
        const float wcl = W[c * C + lane];      // coalesced, L1-resident
        float va[16];
        ((float4*)va)[0] = *(const float4*)&hs[c][p0];
        ((float4*)va)[1] = *(const float4*)&hs[c][p0 + 4];
        ((float4*)va)[2] = *(const float4*)&hs[c][p0 + 8];
        ((float4*)va)[3] = *(const float4*)&hs[c][p0 + 12];
        #pragma unroll
        for (int i = 0; i < 16; ++i) acc[i] = fmaf(va[i], wcl, acc[i]);
    }

    if (dir == 2) {
        #pragma unroll
        for (int i = 0; i < 16; ++i)
            yvb[(size_t)(n0 + p0 + i) * C + lane] = __float2bfloat16(acc[i]);
    } else {
        float* __restrict__ out = (dir == 0) ? xq : yk;
        #pragma unroll
        for (int i = 0; i < 16; ++i)
            out[(size_t)(n0 + p0 + i) * C + lane] = acc[i];
    }
}

// ---------------------------------------------------------------------------
// K1b: xuni (flat-reshape matvec + bn + relu) and xyz packing.
// ---------------------------------------------------------------------------
__global__ __launch_bounds__(256) void aux_kernel(
    const float* __restrict__ x, const float* __restrict__ y_xyz,
    const float* __restrict__ Wu, const float* __restrict__ bu,
    const float* __restrict__ gu, const float* __restrict__ bnu,
    float* __restrict__ xu, float4* __restrict__ pk)
{
    const int lane = threadIdx.x & 63;
    const int wave = threadIdx.x >> 6;

    const float wul = Wu[lane];
    const float bnscale = gu[0] * BN_INV;
    const float bu0 = bu[0], bnu0 = bnu[0];
    #pragma unroll 4
    for (int i = 0; i < 16; ++i) {
        const int m = blockIdx.x * 64 + wave * 16 + i;
        float v = x[m * 64 + lane] * wul;
        #pragma unroll
        for (int off = 32; off > 0; off >>= 1) v += __shfl_xor(v, off, 64);
        if (lane == 0) {
            float u = (v + bu0) * bnscale + bnu0;
            xu[m] = fmaxf(u, 0.0f);
        }
    }
    if (wave == 0) {
        const int p = blockIdx.x * 64 + lane;
        pk[p] = make_float4(y_xyz[p], y_xyz[NPTS + p], y_xyz[2 * NPTS + p], 0.0f);
    }
}

// ---------------------------------------------------------------------------
// K2: partial S[c][k] = sum_n (y_k[idx[n,k]][c] - x_q[n][c]) * xu[n]
// ---------------------------------------------------------------------------
__global__ __launch_bounds__(256) void sred_kernel(
    const float* __restrict__ xq, const float* __restrict__ yk,
    const float* __restrict__ xu, const int* __restrict__ idx,
    float* __restrict__ partG)
{
    const int lane = threadIdx.x & 63;
    const int wave = threadIdx.x >> 6;
    const int gw = blockIdx.x * 4 + wave;
    const int nwv = NB2 * 4;
    float g[K];
    #pragma unroll
    for (int k = 0; k < K; ++k) g[k] = 0.0f;
    for (int n = gw; n < NPTS; n += nwv) {
        const float xuv = xu[n];
        if (xuv != 0.0f) {
            const float xqv = xq[n * C + lane];
            #pragma unroll
            for (int k = 0; k < K; ++k) {
                const int id = idx[n * K + k];
                g[k] = fmaf(yk[id * C + lane] - xqv, xuv, g[k]);
            }
        }
    }
    __shared__ float red[4][K][C];
    #pragma unroll
    for (int k = 0; k < K; ++k) red[wave][k][lane] = g[k];
    __syncthreads();
    if (wave == 0) {
        #pragma unroll
        for (int k = 0; k < K; ++k) {
            float s = red[0][k][lane] + red[1][k][lane] + red[2][k][lane] + red[3][k][lane];
            partG[blockIdx.x * (K * C) + k * C + lane] = s;
        }
    }
}

// ---------------------------------------------------------------------------
// K2a: hierarchical reduce 512 -> 64 partials (deterministic, no atomics)
// ---------------------------------------------------------------------------
__global__ __launch_bounds__(1024) void sred2_kernel(
    const float* __restrict__ partG, float* __restrict__ part2)
{
    const int j = blockIdx.x;       // 0..63
    const int t = threadIdx.x;      // 0..1023
    float s = 0.0f;
    #pragma unroll
    for (int i = 0; i < NB2 / NB2R; ++i)
        s += partG[(size_t)(j + NB2R * i) * (K * C) + t];
    part2[(size_t)j * (K * C) + t] = s;
}

// ---------------------------------------------------------------------------
// K2b: reduce 64 partials, softmax over k -> wd[c][k], awdT[k][c]=a_p[k]*wd
// ---------------------------------------------------------------------------
__global__ __launch_bounds__(1024) void wd_kernel(
    const float* __restrict__ part2, const float* __restrict__ a_p,
    float* __restrict__ wd, float* __restrict__ awdT)
{
    __shared__ float S[K][C];
    const int t = threadIdx.x;          // t = k*64 + c
    {
        float s = 0.0f;
        #pragma unroll 8
        for (int b = 0; b < NB2R; ++b) s += part2[b * (K * C) + t];
        S[0][t] = s;
    }
    __syncthreads();
    if (t < C) {
        const int c = t;
        float v[K];
        float m = -3.402823466e38f;
        #pragma unroll
        for (int k = 0; k < K; ++k) { v[k] = S[k][c]; m = fmaxf(m, v[k]); }
        float sum = 0.0f;
        #pragma unroll
        for (int k = 0; k < K; ++k) { v[k] = expf(v[k] - m); sum += v[k]; }
        const float r = 1.0f / sum;
        #pragma unroll
        for (int k = 0; k < K; ++k) {
            const float wv = v[k] * r;
            wd[c * K + k] = wv;
            awdT[k * C + c] = a_p[k] * wv;
        }
    }
}

// ---------------------------------------------------------------------------
// K3: w_e[n][k] = softmax_k( sum_c y[c][n] * wd[c][k] )
// ---------------------------------------------------------------------------
__global__ __launch_bounds__(256) void we_kernel(
    const float* __restrict__ y, const float* __restrict__ wd,
    float* __restrict__ we)
{
    __shared__ float wds[C][K];
    const int lane = threadIdx.x & 63;
    const int wave = threadIdx.x >> 6;
    for (int i = threadIdx.x; i < C * K; i += 256) wds[0][i] = wd[i];
    __syncthreads();

    const int n = (blockIdx.x * 4 + wave) * 64 + lane;
    float L[K];
    #pragma unroll
    for (int k = 0; k < K; ++k) L[k] = 0.0f;
    for (int c = 0; c < C; ++c) {
        const float yv = y[c * NPTS + n];
        float wa[K];
        ((float4*)wa)[0] = ((const float4*)&wds[c][0])[0];
        ((float4*)wa)[1] = ((const float4*)&wds[c][0])[1];
        ((float4*)wa)[2] = ((const float4*)&wds[c][0])[2];
        ((float4*)wa)[3] = ((const float4*)&wds[c][0])[3];
        #pragma unroll
        for (int k = 0; k < K; ++k) L[k] = fmaf(yv, wa[k], L[k]);
    }
    float m = L[0];
    #pragma unroll
    for (int k = 1; k < K; ++k) m = fmaxf(m, L[k]);
    float sum = 0.0f;
    #pragma unroll
    for (int k = 0; k < K; ++k) { L[k] = expf(L[k] - m); sum += L[k]; }
    const float r = 1.0f / sum;
    float* dst = we + (size_t)n * K;
    ((float4*)dst)[0] = make_float4(L[0]*r, L[1]*r, L[2]*r, L[3]*r);
    ((float4*)dst)[1] = make_float4(L[4]*r, L[5]*r, L[6]*r, L[7]*r);
    ((float4*)dst)[2] = make_float4(L[8]*r, L[9]*r, L[10]*r, L[11]*r);
    ((float4*)dst)[3] = make_float4(L[12]*r, L[13]*r, L[14]*r, L[15]*r);
}

// ---------------------------------------------------------------------------
// K3b: tabulate F_kc(t) (2-layer PWL map of scalar t) at t=i/NTAB, i=0..NTAB
// ---------------------------------------------------------------------------
__global__ __launch_bounds__(64) void tab_kernel(
    const float* __restrict__ awdT, const float* __restrict__ b_p,
    const float* __restrict__ Ww1, const float* __restrict__ bw1,
    const float* __restrict__ Ww2, const float* __restrict__ bw2,
    const float* __restrict__ gw1, const float* __restrict__ bw1b,
    const float* __restrict__ gw2, const float* __restrict__ bw2b,
    float* __restrict__ tab)
{
    const int lane = threadIdx.x;
    const int k  = blockIdx.y;
    const int i0 = blockIdx.x * 16;

    const float aw = awdT[k * C + lane];
    const float bp = b_p[k * C + lane];
    const float gs1 = gw1[lane] * BN_INV, bb1 = bw1b[lane], bw1c = bw1[lane];
    const float gs2 = gw2[lane] * BN_INV, bb2 = bw2b[lane], bw2c = bw2[lane];

    float w1c[C], w2c[C];
    #pragma unroll
    for (int c = 0; c < C; ++c) { w1c[c] = Ww1[c * C + lane]; w2c[c] = Ww2[c * C + lane]; }

    __shared__ float hs[16][C];

    #pragma unroll
    for (int r = 0; r < 16; ++r) {
        const float t = (float)(i0 + r) * (1.0f / NTAB);
        const float wv = fmaf(bp, t, aw);
        hs[r][lane] = fmaxf(fmaf(wv, gs1, bb1), 0.0f);
    }
    __syncthreads();

    float o[16];
    #pragma unroll
    for (int r = 0; r < 16; ++r) o[r] = bw1c;
    #pragma unroll
    for (int c4 = 0; c4 < 16; ++c4) {
        #pragma unroll
        for (int r = 0; r < 16; ++r) {
            const float4 hv = *(const float4*)&hs[r][c4 * 4];
            o[r] = fmaf(hv.x, w1c[c4 * 4 + 0], o[r]);
            o[r] = fmaf(hv.y, w1c[c4 * 4 + 1], o[r]);
            o[r] = fmaf(hv.z, w1c[c4 * 4 + 2], o[r]);
            o[r] = fmaf(hv.w, w1c[c4 * 4 + 3], o[r]);
        }
    }
    __syncthreads();
    #pragma unroll
    for (int r = 0; r < 16; ++r)
        hs[r][lane] = fmaxf(fmaf(o[r], gs2, bb2), 0.0f);
    __syncthreads();
    #pragma unroll
    for (int r = 0; r < 16; ++r) o[r] = bw2c;
    #pragma unroll
    for (int c4 = 0; c4 < 16; ++c4) {
        #pragma unroll
        for (int r = 0; r < 16; ++r) {
            const float4 hv = *(const float4*)&hs[r][c4 * 4];
            o[r] = fmaf(hv.x, w2c[c4 * 4 + 0], o[r]);
            o[r] = fmaf(hv.y, w2c[c4 * 4 + 1], o[r]);
            o[r] = fmaf(hv.z, w2c[c4 * 4 + 2], o[r]);
            o[r] = fmaf(hv.w, w2c[c4 * 4 + 3], o[r]);
        }
    }
    #pragma unroll
    for (int r = 0; r < 16; ++r) {
        const int i = i0 + r;
        if (i <= NTAB) tab[(k * (NTAB + 1) + i) * C + lane] = o[r];
    }
}

// ---------------------------------------------------------------------------
// K4 (hot): per point n (one wave, lane = channel c). Software-pipelined.
// ---------------------------------------------------------------------------
__global__ __launch_bounds__(256) void main3_kernel(
    const int* __restrict__ idx, const float4* __restrict__ pk,
    const __hip_bfloat16* __restrict__ yvb, const float* __restrict__ we,
    const float* __restrict__ tab, const float* __restrict__ d_p,
    const float* __restrict__ Wa1, const float* __restrict__ ba1,
    const float* __restrict__ ga, const float* __restrict__ bna,
    const float* __restrict__ Wa2, const float* __restrict__ ba2,
    const float* __restrict__ Wp1, const float* __restrict__ bp1,
    const float* __restrict__ gp, const float* __restrict__ bnp,
    const float* __restrict__ Wp2, const float* __restrict__ bp2,
    float* __restrict__ out)
{
    const int lane = threadIdx.x & 63;
    const int wave = threadIdx.x >> 6;

    __shared__ float geo[4][K][8];    // [1..3] af-features, [4..6] pr-features
    __shared__ float prm[36];

    if (threadIdx.x < 36) {
        const int t = threadIdx.x;
        float v;
        if (t < 9)       v = Wa1[t];
        else if (t < 12) v = ba1[t - 9];
        else if (t < 21) v = Wp1[t - 12];
        else if (t < 24) v = bp1[t - 21];
        else if (t < 27) v = ga[t - 24];
        else if (t < 30) v = bna[t - 27];
        else if (t < 33) v = gp[t - 30];
        else             v = bnp[t - 33];
        prm[t] = v;
    }
    __syncthreads();

    const float ba2c = ba2[lane], bp2c = bp2[lane];
    float wa2c[3], wp2c[3];
    #pragma unroll
    for (int d = 0; d < 3; ++d) { wa2c[d] = Wa2[d * C + lane]; wp2c[d] = Wp2[d * C + lane]; }
    float dpk[K];
    #pragma unroll
    for (int k = 0; k < K; ++k) dpk[k] = d_p[k * C + lane];

    const int gw = blockIdx.x * 4 + wave;
    const int nwv = gridDim.x * 4;
    const ushort* __restrict__ yvu_base = (const ushort*)yvb;

    // ---- prologue prefetch ----
    int n = gw;
    int idv = idx[n * K + (lane & 15)];
    float4 self = pk[n];
    float4 wev0 = ((const float4*)(we + (size_t)n * K))[0];
    float4 wev1 = ((const float4*)(we + (size_t)n * K))[1];
    float4 wev2 = ((const float4*)(we + (size_t)n * K))[2];
    float4 wev3 = ((const float4*)(we + (size_t)n * K))[3];

    while (n < NPTS) {
        const int n_next = n + nwv;

        // ---- dependent gathers for current point (issued first) ----
        const float4 nb = pk[idv];
        ushort yvu[K];
        #pragma unroll
        for (int k = 0; k < K; ++k) {
            const int idk = __shfl(idv, k, 64);
            yvu[k] = yvu_base[(size_t)idk * C + lane];
        }

        // ---- table loads (depend only on prefetched we) ----
        float wearr[K];
        ((float4*)wearr)[0] = wev0;
        ((float4*)wearr)[1] = wev1;
        ((float4*)wearr)[2] = wev2;
        ((float4*)wearr)[3] = wev3;
        float tv0[K], tv1[K], fr[K];
        #pragma unroll
        for (int k = 0; k < K; ++k) {
            const float u = wearr[k] * (float)NTAB;
            int ic = (int)u;
            ic = (ic < 0) ? 0 : (ic > NTAB - 1 ? NTAB - 1 : ic);
            fr[k] = u - (float)ic;
            const float* tp = tab + ((size_t)(k * (NTAB + 1) + ic) << 6) + lane;
            tv0[k] = tp[0];
            tv1[k] = tp[C];
        }

        // ---- prefetch next point's independent loads ----
        int idv_n = 0;
        float4 self_n = make_float4(0.f, 0.f, 0.f, 0.f);
        float4 wen0 = self_n, wen1 = self_n, wen2 = self_n, wen3 = self_n;
        if (n_next < NPTS) {
            idv_n  = idx[n_next * K + (lane & 15)];
            self_n = pk[n_next];
            wen0 = ((const float4*)(we + (size_t)n_next * K))[0];
            wen1 = ((const float4*)(we + (size_t)n_next * K))[1];
            wen2 = ((const float4*)(we + (size_t)n_next * K))[2];
            wen3 = ((const float4*)(we + (size_t)n_next * K))[3];
        }

        // ---- geometry (all lanes compute for k = lane&15; lanes<16 write) ----
        {
            const float px = nb.x - self.x;
            const float py = nb.y - self.y;
            const float pz = nb.z - self.z;
            const float ed  = sqrtf(px * px + py * py + pz * pz);
            const float exy = sqrtf(px * px + py * py);
            const float cose = safediv_n2n(exy, ed);
            const float cosa = safediv_n2n(py, exy);
            float gv[6];
            #pragma unroll
            for (int d = 0; d < 3; ++d) {
                const float a = ed * prm[d] + cosa * prm[3 + d] + cose * prm[6 + d] + prm[9 + d];
                gv[d] = fmaxf(a * (prm[24 + d] * BN_INV) + prm[27 + d], 0.0f);
                const float p = px * prm[12 + d] + py * prm[15 + d] + pz * prm[18 + d] + prm[21 + d];
                gv[3 + d] = fmaxf(p * (prm[30 + d] * BN_INV) + prm[33 + d], 0.0f);
            }
            if (lane < K) {
                float* g = &geo[wave][lane][0];
                g[1] = gv[0]; g[2] = gv[1]; g[3] = gv[2];
                g[4] = gv[3]; g[5] = gv[4]; g[6] = gv[5];
            }
        }

        // ---- w2 lerp + softmax over k ----
        float w2[K];
        #pragma unroll
        for (int k = 0; k < K; ++k) w2[k] = fmaf(fr[k], tv1[k] - tv0[k], tv0[k]);
        float m = w2[0];
        #pragma unroll
        for (int k = 1; k < K; ++k) m = fmaxf(m, w2[k]);
        float sum = 0.0f;
        #pragma unroll
        for (int k = 0; k < K; ++k) { w2[k] = __expf(w2[k] - m); sum += w2[k]; }
        const float r = 1.0f / sum;

        // ---- epilogue ----
        float acc = 0.0f;
        #pragma unroll
        for (int k = 0; k < K; ++k) {
            const float4 g0 = *(const float4*)&geo[wave][k][0];
            const float4 g1 = *(const float4*)&geo[wave][k][4];
            const float afc = fmaf(g0.y, wa2c[0], fmaf(g0.z, wa2c[1], fmaf(g0.w, wa2c[2], ba2c)));
            float prc = fmaf(g1.x, wp2c[0], fmaf(g1.y, wp2c[1], fmaf(g1.z, wp2c[2], bp2c)));
            prc = fmaf(dpk[k], afc, prc);
            const float yvf = __uint_as_float((unsigned)yvu[k] << 16);
            acc = fmaf(yvf + prc, w2[k] * r, acc);
        }
        out[(size_t)n * C + lane] = acc;

        // ---- rotate pipeline ----
        n = n_next;
        idv = idv_n;
        self = self_n;
        wev0 = wen0; wev1 = wen1; wev2 = wen2; wev3 = wen3;
    }
}

// ---------------------------------------------------------------------------
extern "C" void kernel_launch(void* const* d_in, const int* in_sizes, int n_in,
                              void* d_out, int out_size, void* d_ws, size_t ws_size,
                              hipStream_t stream)
{
    (void)in_sizes; (void)n_in; (void)out_size; (void)ws_size;
    const float* x     = (const float*)d_in[0];
    const float* y     = (const float*)d_in[1];
    const float* y_xyz = (const float*)d_in[2];
    const int*   idx   = (const int*)d_in[3];
    const float* Wq = (const float*)d_in[4];  const float* bq = (const float*)d_in[5];
    const float* Wk = (const float*)d_in[6];  const float* bk = (const float*)d_in[7];
    const float* Wv = (const float*)d_in[8];  const float* bv = (const float*)d_in[9];
    const float* Wu = (const float*)d_in[10]; const float* bu = (const float*)d_in[11];
    const float* gu = (const float*)d_in[12]; const float* bnu = (const float*)d_in[13];
    const float* Wp1 = (const float*)d_in[14]; const float* bp1 = (const float*)d_in[15];
    const float* gp  = (const float*)d_in[16]; const float* bnp = (const float*)d_in[17];
    const float* Wp2 = (const float*)d_in[18]; const float* bp2 = (const float*)d_in[19];
    const float* Wa1 = (const float*)d_in[20]; const float* ba1 = (const float*)d_in[21];
    const float* ga  = (const float*)d_in[22]; const float* bna = (const float*)d_in[23];
    const float* Wa2 = (const float*)d_in[24]; const float* ba2 = (const float*)d_in[25];
    const float* gw1 = (const float*)d_in[26]; const float* bw1b = (const float*)d_in[27];
    const float* Ww1 = (const float*)d_in[28]; const float* bw1 = (const float*)d_in[29];
    const float* gw2 = (const float*)d_in[30]; const float* bw2b = (const float*)d_in[31];
    const float* Ww2 = (const float*)d_in[32]; const float* bw2 = (const float*)d_in[33];
    const float* a_p = (const float*)d_in[34];
    const float* b_p = (const float*)d_in[35];
    const float* d_p = (const float*)d_in[36];
    float* out = (float*)d_out;

    float* ws = (float*)d_ws;
    // layout (floats): xq 2M | yk 2M | yv(bf16) 1M | pk 128K(f4) | xu 32K |
    //                  partG 512K | part2 64K | wd 1K | awdT 1K
    float* xq    = ws;                            // dead after sred
    float* we    = ws;                            // aliases xq (written later)
    float* yk    = ws + 2097152;                  // dead after sred
    float* tab   = ws + 2097152;                  // aliases yk (written later)
    __hip_bfloat16* yvb = (__hip_bfloat16*)(ws + 2 * 2097152);
    float4* pk   = (float4*)(ws + 2 * 2097152 + 1048576);
    float* xu    = ws + 2 * 2097152 + 1048576 + 131072;
    float* partG = xu + NPTS;                     // 512*1024
    float* part2 = partG + NB2 * K * C;           // 64*1024
    float* wd    = part2 + NB2R * K * C;          // 1024
    float* awdT  = wd + C * K;                    // 1024

    proj3_kernel<<<dim3(NPTS / 64, 3), 256, 0, stream>>>(
        x, y, Wq, bq, Wk, bk, Wv, bv, xq, yk, yvb);
    aux_kernel<<<NPTS / 64, 256, 0, stream>>>(x, y_xyz, Wu, bu, gu, bnu, xu, pk);
    sred_kernel<<<NB2, 256, 0, stream>>>(xq, yk, xu, idx, partG);
    sred2_kernel<<<NB2R, 1024, 0, stream>>>(partG, part2);
    wd_kernel<<<1, 1024, 0, stream>>>(part2, a_p, wd, awdT);
    we_kernel<<<NPTS / 256, 256, 0, stream>>>(y, wd, we);
    tab_kernel<<<dim3(33, 16), 64, 0, stream>>>(awdT, b_p, Ww1, bw1, Ww2, bw2,
                                                gw1, bw1b, gw2, bw2b, tab);
    main3_kernel<<<2048, 256, 0, stream>>>(idx, pk, yvb, we, tab, d_p,
        Wa1, ba1, ga, bna, Wa2, ba2, Wp1, bp1, gp, bnp, Wp2, bp2, out);
}

// Round 6
// 112.481 us; speedup vs baseline: 1.4288x; 1.1612x over previous
//
#include <hip/hip_runtime.h>
#include <hip/hip_bf16.h>
#include <math.h>

#define NPTS 32768
#define C 64
#define K 16
#define NB2 512           // sred partial blocks
#define NB2R 64           // after sred2 hierarchical reduce
#define NTAB 512          // table cells for the per-k PWL function F_kc(t)
#define BN_INV 0.99999500003749968f   // 1/sqrt(1+1e-5)

__device__ __forceinline__ float safediv_n2n(float a, float b) {
    float q = a / b;
    if (isnan(q)) return 0.0f;
    if (isinf(q)) return copysignf(3.402823466e38f, q);
    return q;
}

__device__ __forceinline__ float bf16_to_f(ushort u) {
    return __uint_as_float((unsigned)u << 16);
}

// ---------------------------------------------------------------------------
// K1: projections. grid (NPTS/64, 3), block 256 (4 waves).
// LDS-staged activation tile; wave computes 16 points, lane = output col.
// dir 0 -> xq (fp32), dir 1 -> ykb (bf16), dir 2 -> yvb (bf16).
// ---------------------------------------------------------------------------
__global__ __launch_bounds__(256) void proj3_kernel(
    const float* __restrict__ x, const float* __restrict__ y,
    const float* __restrict__ Wq, const float* __restrict__ bq,
    const float* __restrict__ Wk, const float* __restrict__ bk,
    const float* __restrict__ Wv, const float* __restrict__ bv,
    float* __restrict__ xq, __hip_bfloat16* __restrict__ ykb,
    __hip_bfloat16* __restrict__ yvb)
{
    const int dir = blockIdx.y;
    const float* __restrict__ in   = (dir == 0) ? x  : y;
    const float* __restrict__ W    = (dir == 0) ? Wq : (dir == 1) ? Wk : Wv;
    const float* __restrict__ bias = (dir == 0) ? bq : (dir == 1) ? bk : bv;

    const int lane = threadIdx.x & 63;
    const int wave = threadIdx.x >> 6;
    const int n0 = blockIdx.x * 64;

    __shared__ float hs[C][C];          // [c][n_local], 16 KB

    #pragma unroll
    for (int i = 0; i < 16; ++i) {
        const int c = i * 4 + wave;
        hs[c][lane] = in[(size_t)c * NPTS + n0 + lane];
    }
    __syncthreads();

    const int p0 = wave * 16;
    float acc[16];
    const float b = bias[lane];
    #pragma unroll
    for (int i = 0; i < 16; ++i) acc[i] = b;

    #pragma unroll
    for (int c = 0; c < C; ++c) {
        const float wcl = W[c * C + lane];
        float va[16];
        ((float4*)va)[0] = *(const float4*)&hs[c][p0];
        ((float4*)va)[1] = *(const float4*)&hs[c][p0 + 4];
        ((float4*)va)[2] = *(const float4*)&hs[c][p0 + 8];
        ((float4*)va)[3] = *(const float4*)&hs[c][p0 + 12];
        #pragma unroll
        for (int i = 0; i < 16; ++i) acc[i] = fmaf(va[i], wcl, acc[i]);
    }

    if (dir == 0) {
        #pragma unroll
        for (int i = 0; i < 16; ++i)
            xq[(size_t)(n0 + p0 + i) * C + lane] = acc[i];
    } else {
        __hip_bfloat16* __restrict__ dst = (dir == 1) ? ykb : yvb;
        #pragma unroll
        for (int i = 0; i < 16; ++i)
            dst[(size_t)(n0 + p0 + i) * C + lane] = __float2bfloat16(acc[i]);
    }
}

// ---------------------------------------------------------------------------
// K1b: xuni (flat-reshape matvec + bn + relu) and xyz packing.
// ---------------------------------------------------------------------------
__global__ __launch_bounds__(256) void aux_kernel(
    const float* __restrict__ x, const float* __restrict__ y_xyz,
    const float* __restrict__ Wu, const float* __restrict__ bu,
    const float* __restrict__ gu, const float* __restrict__ bnu,
    float* __restrict__ xu, float4* __restrict__ pk)
{
    const int lane = threadIdx.x & 63;
    const int wave = threadIdx.x >> 6;

    const float wul = Wu[lane];
    const float bnscale = gu[0] * BN_INV;
    const float bu0 = bu[0], bnu0 = bnu[0];
    #pragma unroll 4
    for (int i = 0; i < 16; ++i) {
        const int m = blockIdx.x * 64 + wave * 16 + i;
        float v = x[m * 64 + lane] * wul;
        #pragma unroll
        for (int off = 32; off > 0; off >>= 1) v += __shfl_xor(v, off, 64);
        if (lane == 0) {
            float u = (v + bu0) * bnscale + bnu0;
            xu[m] = fmaxf(u, 0.0f);
        }
    }
    if (wave == 0) {
        const int p = blockIdx.x * 64 + lane;
        pk[p] = make_float4(y_xyz[p], y_xyz[NPTS + p], y_xyz[2 * NPTS + p], 0.0f);
    }
}

// ---------------------------------------------------------------------------
// K2: partial S[c][k] = sum_n (y_k[idx[n,k]][c] - x_q[n][c]) * xu[n]
// Uniform wave index (readfirstlane) -> xu / idx rows via s_load; neighbor
// ids in SGPRs -> gathers are saddr + shared lane offset; y_k in bf16
// (128B rows, 4MB total -> L2-friendly). Uniform branch skips xu==0 rows.
// ---------------------------------------------------------------------------
__global__ __launch_bounds__(256) void sred_kernel(
    const float* __restrict__ xq, const __hip_bfloat16* __restrict__ ykb,
    const float* __restrict__ xu, const int* __restrict__ idx,
    float* __restrict__ partG)
{
    const int lane = threadIdx.x & 63;
    const int wv = __builtin_amdgcn_readfirstlane(threadIdx.x >> 6);
    const int gw = blockIdx.x * 4 + wv;
    const int nwv = NB2 * 4;
    const ushort* __restrict__ yku = (const ushort*)ykb;

    float g[K];
    #pragma unroll
    for (int k = 0; k < K; ++k) g[k] = 0.0f;

    for (int n = gw; n < NPTS; n += nwv) {
        const float xuv = xu[n];                       // uniform (s_load)
        if (xuv != 0.0f) {                             // uniform branch
            const float xqv = xq[(size_t)n * C + lane];
            const int4* ir = (const int4*)(idx + (size_t)n * K);
            const int4 i0 = ir[0], i1 = ir[1], i2 = ir[2], i3 = ir[3];
            int ids[K] = { i0.x, i0.y, i0.z, i0.w, i1.x, i1.y, i1.z, i1.w,
                           i2.x, i2.y, i2.z, i2.w, i3.x, i3.y, i3.z, i3.w };
            #pragma unroll
            for (int k = 0; k < K; ++k) {
                const float ykv = bf16_to_f(yku[(size_t)ids[k] * C + lane]);
                g[k] = fmaf(ykv - xqv, xuv, g[k]);
            }
        }
    }

    __shared__ float red[4][K][C];
    #pragma unroll
    for (int k = 0; k < K; ++k) red[wv][k][lane] = g[k];
    __syncthreads();
    if (wv == 0) {
        #pragma unroll
        for (int k = 0; k < K; ++k) {
            float s = red[0][k][lane] + red[1][k][lane] + red[2][k][lane] + red[3][k][lane];
            partG[blockIdx.x * (K * C) + k * C + lane] = s;
        }
    }
}

// ---------------------------------------------------------------------------
// K2a: hierarchical reduce 512 -> 64 partials (deterministic, no atomics)
// ---------------------------------------------------------------------------
__global__ __launch_bounds__(1024) void sred2_kernel(
    const float* __restrict__ partG, float* __restrict__ part2)
{
    const int j = blockIdx.x;       // 0..63
    const int t = threadIdx.x;      // 0..1023
    float s = 0.0f;
    #pragma unroll
    for (int i = 0; i < NB2 / NB2R; ++i)
        s += partG[(size_t)(j + NB2R * i) * (K * C) + t];
    part2[(size_t)j * (K * C) + t] = s;
}

// ---------------------------------------------------------------------------
// K2b: reduce 64 partials, softmax over k -> wd[c][k], awdT[k][c]=a_p[k]*wd
// ---------------------------------------------------------------------------
__global__ __launch_bounds__(1024) void wd_kernel(
    const float* __restrict__ part2, const float* __restrict__ a_p,
    float* __restrict__ wd, float* __restrict__ awdT)
{
    __shared__ float S[K][C];
    const int t = threadIdx.x;          // t = k*64 + c
    {
        float s = 0.0f;
        #pragma unroll 8
        for (int b = 0; b < NB2R; ++b) s += part2[b * (K * C) + t];
        S[0][t] = s;
    }
    __syncthreads();
    if (t < C) {
        const int c = t;
        float v[K];
        float m = -3.402823466e38f;
        #pragma unroll
        for (int k = 0; k < K; ++k) { v[k] = S[k][c]; m = fmaxf(m, v[k]); }
        float sum = 0.0f;
        #pragma unroll
        for (int k = 0; k < K; ++k) { v[k] = expf(v[k] - m); sum += v[k]; }
        const float r = 1.0f / sum;
        #pragma unroll
        for (int k = 0; k < K; ++k) {
            const float wv = v[k] * r;
            wd[c * K + k] = wv;
            awdT[k * C + c] = a_p[k] * wv;
        }
    }
}

// ---------------------------------------------------------------------------
// K3: w_e[n][k] = softmax_k( sum_c y[c][n] * wd[c][k] )
// ---------------------------------------------------------------------------
__global__ __launch_bounds__(256) void we_kernel(
    const float* __restrict__ y, const float* __restrict__ wd,
    float* __restrict__ we)
{
    __shared__ float wds[C][K];
    const int lane = threadIdx.x & 63;
    const int wave = threadIdx.x >> 6;
    for (int i = threadIdx.x; i < C * K; i += 256) wds[0][i] = wd[i];
    __syncthreads();

    const int n = (blockIdx.x * 4 + wave) * 64 + lane;
    float L[K];
    #pragma unroll
    for (int k = 0; k < K; ++k) L[k] = 0.0f;
    for (int c = 0; c < C; ++c) {
        const float yv = y[c * NPTS + n];
        float wa[K];
        ((float4*)wa)[0] = ((const float4*)&wds[c][0])[0];
        ((float4*)wa)[1] = ((const float4*)&wds[c][0])[1];
        ((float4*)wa)[2] = ((const float4*)&wds[c][0])[2];
        ((float4*)wa)[3] = ((const float4*)&wds[c][0])[3];
        #pragma unroll
        for (int k = 0; k < K; ++k) L[k] = fmaf(yv, wa[k], L[k]);
    }
    float m = L[0];
    #pragma unroll
    for (int k = 1; k < K; ++k) m = fmaxf(m, L[k]);
    float sum = 0.0f;
    #pragma unroll
    for (int k = 0; k < K; ++k) { L[k] = expf(L[k] - m); sum += L[k]; }
    const float r = 1.0f / sum;
    float* dst = we + (size_t)n * K;
    ((float4*)dst)[0] = make_float4(L[0]*r, L[1]*r, L[2]*r, L[3]*r);
    ((float4*)dst)[1] = make_float4(L[4]*r, L[5]*r, L[6]*r, L[7]*r);
    ((float4*)dst)[2] = make_float4(L[8]*r, L[9]*r, L[10]*r, L[11]*r);
    ((float4*)dst)[3] = make_float4(L[12]*r, L[13]*r, L[14]*r, L[15]*r);
}

// ---------------------------------------------------------------------------
// K3b: tabulate F_kc(t) (2-layer PWL map of scalar t) at t=i/NTAB, i=0..NTAB
// ---------------------------------------------------------------------------
__global__ __launch_bounds__(64) void tab_kernel(
    const float* __restrict__ awdT, const float* __restrict__ b_p,
    const float* __restrict__ Ww1, const float* __restrict__ bw1,
    const float* __restrict__ Ww2, const float* __restrict__ bw2,
    const float* __restrict__ gw1, const float* __restrict__ bw1b,
    const float* __restrict__ gw2, const float* __restrict__ bw2b,
    float* __restrict__ tab)
{
    const int lane = threadIdx.x;
    const int k  = blockIdx.y;
    const int i0 = blockIdx.x * 16;

    const float aw = awdT[k * C + lane];
    const float bp = b_p[k * C + lane];
    const float gs1 = gw1[lane] * BN_INV, bb1 = bw1b[lane], bw1c = bw1[lane];
    const float gs2 = gw2[lane] * BN_INV, bb2 = bw2b[lane], bw2c = bw2[lane];

    float w1c[C], w2c[C];
    #pragma unroll
    for (int c = 0; c < C; ++c) { w1c[c] = Ww1[c * C + lane]; w2c[c] = Ww2[c * C + lane]; }

    __shared__ float hs[16][C];

    #pragma unroll
    for (int r = 0; r < 16; ++r) {
        const float t = (float)(i0 + r) * (1.0f / NTAB);
        const float wv = fmaf(bp, t, aw);
        hs[r][lane] = fmaxf(fmaf(wv, gs1, bb1), 0.0f);
    }
    __syncthreads();

    float o[16];
    #pragma unroll
    for (int r = 0; r < 16; ++r) o[r] = bw1c;
    #pragma unroll
    for (int c4 = 0; c4 < 16; ++c4) {
        #pragma unroll
        for (int r = 0; r < 16; ++r) {
            const float4 hv = *(const float4*)&hs[r][c4 * 4];
            o[r] = fmaf(hv.x, w1c[c4 * 4 + 0], o[r]);
            o[r] = fmaf(hv.y, w1c[c4 * 4 + 1], o[r]);
            o[r] = fmaf(hv.z, w1c[c4 * 4 + 2], o[r]);
            o[r] = fmaf(hv.w, w1c[c4 * 4 + 3], o[r]);
        }
    }
    __syncthreads();
    #pragma unroll
    for (int r = 0; r < 16; ++r)
        hs[r][lane] = fmaxf(fmaf(o[r], gs2, bb2), 0.0f);
    __syncthreads();
    #pragma unroll
    for (int r = 0; r < 16; ++r) o[r] = bw2c;
    #pragma unroll
    for (int c4 = 0; c4 < 16; ++c4) {
        #pragma unroll
        for (int r = 0; r < 16; ++r) {
            const float4 hv = *(const float4*)&hs[r][c4 * 4];
            o[r] = fmaf(hv.x, w2c[c4 * 4 + 0], o[r]);
            o[r] = fmaf(hv.y, w2c[c4 * 4 + 1], o[r]);
            o[r] = fmaf(hv.z, w2c[c4 * 4 + 2], o[r]);
            o[r] = fmaf(hv.w, w2c[c4 * 4 + 3], o[r]);
        }
    }
    #pragma unroll
    for (int r = 0; r < 16; ++r) {
        const int i = i0 + r;
        if (i <= NTAB) tab[(k * (NTAB + 1) + i) * C + lane] = o[r];
    }
}

// ---------------------------------------------------------------------------
// K4 (hot): ONE point per wave (grid 8192 x 4 waves), lane = channel c.
// Wave-uniform data (idx row, we row, pk[n]) via SGPR loads; neighbor ids in
// SGPRs -> gathers use saddr + shared lane offset (no per-lane 64-bit math,
// no shfl). Latency hidden by TLP, not software pipelining.
// ---------------------------------------------------------------------------
__global__ __launch_bounds__(256, 5) void main4_kernel(
    const int* __restrict__ idx, const float4* __restrict__ pk,
    const __hip_bfloat16* __restrict__ yvb, const float* __restrict__ we,
    const float* __restrict__ tab, const float* __restrict__ d_p,
    const float* __restrict__ Wa1, const float* __restrict__ ba1,
    const float* __restrict__ ga, const float* __restrict__ bna,
    const float* __restrict__ Wa2, const float* __restrict__ ba2,
    const float* __restrict__ Wp1, const float* __restrict__ bp1,
    const float* __restrict__ gp, const float* __restrict__ bnp,
    const float* __restrict__ Wp2, const float* __restrict__ bp2,
    float* __restrict__ out)
{
    const int lane = threadIdx.x & 63;
    const int wv = __builtin_amdgcn_readfirstlane(threadIdx.x >> 6);
    const int n = blockIdx.x * 4 + wv;                 // uniform point id

    __shared__ float geo[4][K][8];
    __shared__ float prm[36];

    if (threadIdx.x < 36) {
        const int t = threadIdx.x;
        float v;
        if (t < 9)       v = Wa1[t];
        else if (t < 12) v = ba1[t - 9];
        else if (t < 21) v = Wp1[t - 12];
        else if (t < 24) v = bp1[t - 21];
        else if (t < 27) v = ga[t - 24];
        else if (t < 30) v = bna[t - 27];
        else if (t < 33) v = gp[t - 30];
        else             v = bnp[t - 33];
        prm[t] = v;
    }
    __syncthreads();

    // ---- uniform loads (scalar path) ----
    const int4* ir = (const int4*)(idx + (size_t)n * K);
    const int4 i0 = ir[0], i1 = ir[1], i2 = ir[2], i3 = ir[3];
    const int ids[K] = { i0.x, i0.y, i0.z, i0.w, i1.x, i1.y, i1.z, i1.w,
                         i2.x, i2.y, i2.z, i2.w, i3.x, i3.y, i3.z, i3.w };
    const float4 self = pk[n];
    const float4 wv0 = ((const float4*)(we + (size_t)n * K))[0];
    const float4 wv1 = ((const float4*)(we + (size_t)n * K))[1];
    const float4 wv2 = ((const float4*)(we + (size_t)n * K))[2];
    const float4 wv3 = ((const float4*)(we + (size_t)n * K))[3];
    const float wearr[K] = { wv0.x, wv0.y, wv0.z, wv0.w, wv1.x, wv1.y, wv1.z, wv1.w,
                             wv2.x, wv2.y, wv2.z, wv2.w, wv3.x, wv3.y, wv3.z, wv3.w };

    // ---- per-lane gathers: yv rows (saddr + lane*2) ----
    const ushort* __restrict__ yvu_base = (const ushort*)yvb;
    ushort yvu[K];
    #pragma unroll
    for (int k = 0; k < K; ++k)
        yvu[k] = yvu_base[(size_t)ids[k] * C + lane];

    // ---- geometry (lanes compute k = lane&15; lanes<16 write LDS) ----
    {
        const int idv = (idx + (size_t)n * K)[lane & 15];   // per-lane
        const float4 nb = pk[idv];
        const float px = nb.x - self.x;
        const float py = nb.y - self.y;
        const float pz = nb.z - self.z;
        const float ed  = sqrtf(px * px + py * py + pz * pz);
        const float exy = sqrtf(px * px + py * py);
        const float cose = safediv_n2n(exy, ed);
        const float cosa = safediv_n2n(py, exy);
        float gv[6];
        #pragma unroll
        for (int d = 0; d < 3; ++d) {
            const float a = ed * prm[d] + cosa * prm[3 + d] + cose * prm[6 + d] + prm[9 + d];
            gv[d] = fmaxf(a * (prm[24 + d] * BN_INV) + prm[27 + d], 0.0f);
            const float p = px * prm[12 + d] + py * prm[15 + d] + pz * prm[18 + d] + prm[21 + d];
            gv[3 + d] = fmaxf(p * (prm[30 + d] * BN_INV) + prm[33 + d], 0.0f);
        }
        if (lane < K) {
            float* g = &geo[wv][lane][0];
            g[1] = gv[0]; g[2] = gv[1]; g[3] = gv[2];
            g[4] = gv[3]; g[5] = gv[4]; g[6] = gv[5];
        }
    }

    // ---- w2[k] via table lerp, two batches of 8 (register diet) ----
    float w2[K];
    #pragma unroll
    for (int h = 0; h < 2; ++h) {
        float tv0[8], tv1[8], fr[8];
        #pragma unroll
        for (int j = 0; j < 8; ++j) {
            const int k = h * 8 + j;
            const float u = wearr[k] * (float)NTAB;
            int ic = (int)u;
            ic = (ic < 0) ? 0 : (ic > NTAB - 1 ? NTAB - 1 : ic);
            fr[j] = u - (float)ic;
            const float* tp = tab + ((size_t)(k * (NTAB + 1) + ic) << 6) + lane;
            tv0[j] = tp[0];
            tv1[j] = tp[C];
        }
        #pragma unroll
        for (int j = 0; j < 8; ++j)
            w2[h * 8 + j] = fmaf(fr[j], tv1[j] - tv0[j], tv0[j]);
    }

    // ---- softmax over k ----
    float m = w2[0];
    #pragma unroll
    for (int k = 1; k < K; ++k) m = fmaxf(m, w2[k]);
    float sum = 0.0f;
    #pragma unroll
    for (int k = 0; k < K; ++k) { w2[k] = __expf(w2[k] - m); sum += w2[k]; }
    const float r = 1.0f / sum;

    // ---- per-lane params ----
    const float ba2c = ba2[lane], bp2c = bp2[lane];
    float wa2c[3], wp2c[3];
    #pragma unroll
    for (int d = 0; d < 3; ++d) { wa2c[d] = Wa2[d * C + lane]; wp2c[d] = Wp2[d * C + lane]; }

    // ---- epilogue: out = sum_k (y_v_gather + p_r) * w ----
    float acc = 0.0f;
    #pragma unroll
    for (int k = 0; k < K; ++k) {
        const float4 g0 = *(const float4*)&geo[wv][k][0];
        const float4 g1 = *(const float4*)&geo[wv][k][4];
        const float afc = fmaf(g0.y, wa2c[0], fmaf(g0.z, wa2c[1], fmaf(g0.w, wa2c[2], ba2c)));
        float prc = fmaf(g1.x, wp2c[0], fmaf(g1.y, wp2c[1], fmaf(g1.z, wp2c[2], bp2c)));
        prc = fmaf(d_p[k * C + lane], afc, prc);
        acc = fmaf(bf16_to_f(yvu[k]) + prc, w2[k] * r, acc);
    }
    out[(size_t)n * C + lane] = acc;
}

// ---------------------------------------------------------------------------
extern "C" void kernel_launch(void* const* d_in, const int* in_sizes, int n_in,
                              void* d_out, int out_size, void* d_ws, size_t ws_size,
                              hipStream_t stream)
{
    (void)in_sizes; (void)n_in; (void)out_size; (void)ws_size;
    const float* x     = (const float*)d_in[0];
    const float* y     = (const float*)d_in[1];
    const float* y_xyz = (const float*)d_in[2];
    const int*   idx   = (const int*)d_in[3];
    const float* Wq = (const float*)d_in[4];  const float* bq = (const float*)d_in[5];
    const float* Wk = (const float*)d_in[6];  const float* bk = (const float*)d_in[7];
    const float* Wv = (const float*)d_in[8];  const float* bv = (const float*)d_in[9];
    const float* Wu = (const float*)d_in[10]; const float* bu = (const float*)d_in[11];
    const float* gu = (const float*)d_in[12]; const float* bnu = (const float*)d_in[13];
    const float* Wp1 = (const float*)d_in[14]; const float* bp1 = (const float*)d_in[15];
    const float* gp  = (const float*)d_in[16]; const float* bnp = (const float*)d_in[17];
    const float* Wp2 = (const float*)d_in[18]; const float* bp2 = (const float*)d_in[19];
    const float* Wa1 = (const float*)d_in[20]; const float* ba1 = (const float*)d_in[21];
    const float* ga  = (const float*)d_in[22]; const float* bna = (const float*)d_in[23];
    const float* Wa2 = (const float*)d_in[24]; const float* ba2 = (const float*)d_in[25];
    const float* gw1 = (const float*)d_in[26]; const float* bw1b = (const float*)d_in[27];
    const float* Ww1 = (const float*)d_in[28]; const float* bw1 = (const float*)d_in[29];
    const float* gw2 = (const float*)d_in[30]; const float* bw2b = (const float*)d_in[31];
    const float* Ww2 = (const float*)d_in[32]; const float* bw2 = (const float*)d_in[33];
    const float* a_p = (const float*)d_in[34];
    const float* b_p = (const float*)d_in[35];
    const float* d_p = (const float*)d_in[36];
    float* out = (float*)d_out;

    float* ws = (float*)d_ws;
    // layout (float offsets):
    float* xq    = ws;                                  // 2M floats; dead after sred
    float* we    = ws;                                  // aliases xq (written later)
    float* tab   = ws + 2097152;                        // 525312
    __hip_bfloat16* ykb = (__hip_bfloat16*)(ws + 2622464);   // 1M floats (bf16 4MB)
    __hip_bfloat16* yvb = (__hip_bfloat16*)(ws + 3671040);   // 1M floats (bf16 4MB)
    float4* pk   = (float4*)(ws + 4719616);             // 131072 floats
    float* xu    = ws + 4850688;                        // 32768
    float* partG = ws + 4883456;                        // 524288
    float* part2 = ws + 5407744;                        // 65536
    float* wd    = ws + 5473280;                        // 1024
    float* awdT  = ws + 5474304;                        // 1024

    proj3_kernel<<<dim3(NPTS / 64, 3), 256, 0, stream>>>(
        x, y, Wq, bq, Wk, bk, Wv, bv, xq, ykb, yvb);
    aux_kernel<<<NPTS / 64, 256, 0, stream>>>(x, y_xyz, Wu, bu, gu, bnu, xu, pk);
    sred_kernel<<<NB2, 256, 0, stream>>>(xq, ykb, xu, idx, partG);
    sred2_kernel<<<NB2R, 1024, 0, stream>>>(partG, part2);
    wd_kernel<<<1, 1024, 0, stream>>>(part2, a_p, wd, awdT);
    we_kernel<<<NPTS / 256, 256, 0, stream>>>(y, wd, we);
    tab_kernel<<<dim3(33, 16), 64, 0, stream>>>(awdT, b_p, Ww1, bw1, Ww2, bw2,
                                                gw1, bw1b, gw2, bw2b, tab);
    main4_kernel<<<NPTS / 4, 256, 0, stream>>>(idx, pk, yvb, we, tab, d_p,
        Wa1, ba1, ga, bna, Wa2, ba2, Wp1, bp1, gp, bnp, Wp2, bp2, out);
}